// Round 5
// baseline (151.044 us; speedup 1.0000x reference)
//
#include <hip/hip_runtime.h>

// Problem constants
static constexpr int B_ = 64, A_ = 32, BOARD_ = 64, D_ = 5;
static constexpr long long FACN = (long long)B_ * A_ * BOARD_ * BOARD_ * D_; // 41,943,040
static constexpr long long CHN  = (long long)B_ * A_ * BOARD_ * BOARD_;      // 8,388,608
static constexpr int NAG = B_ * A_;                                          // 2048

// exp(-1/50), exp(-1/20)
static constexpr float FAC_DECAY = 0.9801986733067553f;
static constexpr float INH_DECAY = 0.9512294245007140f;

// Native clang vector type — required by __builtin_nontemporal_load/store.
typedef float f32x4 __attribute__((ext_vector_type(4)));

// Block-uniform region assignment: blocks [0,931) -> fac, [931,1862) -> inh,
// [1862,2048) -> ch (proportional to region sizes). Inside a block the loop is
// a pure strided copy-scale: loop-invariant src/dst/scale (SGPRs), 4-deep
// unroll for MLP, plain loads (m13 copy-ceiling pattern), nontemporal stores.
__global__ __launch_bounds__(256) void bulk_kernel(
    const f32x4* __restrict__ fac_in, const f32x4* __restrict__ inh_in,
    const f32x4* __restrict__ ch_in, f32x4* __restrict__ out)
{
    const int FACV = (int)(FACN / 4);       // 10,485,760 vectors
    const int CHV  = (int)(CHN / 4);        //  2,097,152 vectors
    const int GF = 931, GC = 186;           // 931+931+186 = 2048 blocks

    const f32x4* __restrict__ src;
    f32x4* __restrict__ dst;
    int V, nb, rb;
    float s;
    int bid = blockIdx.x;
    if (bid < GF) {
        src = fac_in; dst = out;             V = FACV; s = FAC_DECAY; nb = GF; rb = bid;
    } else if (bid < 2 * GF) {
        src = inh_in; dst = out + FACV;      V = FACV; s = INH_DECAY; nb = GF; rb = bid - GF;
    } else {
        src = ch_in;  dst = out + 2 * FACV;  V = CHV;  s = 0.9f;      nb = GC; rb = bid - 2 * GF;
    }

    const int S = nb * 256;
    int i = rb * 256 + threadIdx.x;
    for (; i + 3 * S < V; i += 4 * S) {
        f32x4 a = src[i];
        f32x4 b = src[i + S];
        f32x4 c = src[i + 2 * S];
        f32x4 d = src[i + 3 * S];
        a *= s; b *= s; c *= s; d *= s;
        __builtin_nontemporal_store(a, &dst[i]);
        __builtin_nontemporal_store(b, &dst[i + S]);
        __builtin_nontemporal_store(c, &dst[i + 2 * S]);
        __builtin_nontemporal_store(d, &dst[i + 3 * S]);
    }
    for (; i < V; i += S) {
        f32x4 a = src[i];
        a *= s;
        __builtin_nontemporal_store(a, &dst[i]);
    }
}

// Per-agent tail: the scatter index (b,a,y,x) is unique per (b,a) -> no atomics.
// Runs after bulk_kernel (stream-ordered); overwrites the scattered cells with
// decayed+added values computed from the ORIGINAL inputs, and writes safety.
// The collisions-dtype sniff is done per-block in parallel (reads 2048 bytes =
// smallest possible encoding of the 2048-entry bool buffer -> always in bounds).
__global__ __launch_bounds__(256) void agent_kernel(
    const float* __restrict__ pos, const float* __restrict__ goal,
    const float* __restrict__ spike,
    const float* __restrict__ fac_in, const float* __restrict__ inh_in,
    const float* __restrict__ ch_in,
    const void* __restrict__ coll,
    float* __restrict__ out)
{
    // ---- parallel dtype sniff (benign-race shared flags) ----
    __shared__ int s_w4, s_h2;
    if (threadIdx.x == 0) { s_w4 = 1; s_h2 = 1; }
    __syncthreads();
    {
        const unsigned int* cw = (const unsigned int*)coll;
        for (int k = threadIdx.x; k < 512; k += 256) {
            unsigned int w = cw[k];
            if (!(w == 0u || w == 1u || w == 0x3F800000u)) s_w4 = 0;
            unsigned int lo = w & 0xFFFFu, hi = w >> 16;
            if (!((lo == 0u || lo == 1u || lo == 0x3F80u || lo == 0x3C00u) &&
                  (hi == 0u || hi == 1u || hi == 0x3F80u || hi == 0x3C00u)))
                s_h2 = 0;
        }
    }
    __syncthreads();
    const int f = s_w4 ? 4 : (s_h2 ? 2 : 1);

    int idx = blockIdx.x * blockDim.x + threadIdx.x;
    if (idx >= NAG) return;

    float px = pos[idx * 2 + 0];
    float py = pos[idx * 2 + 1];
    int x = min(BOARD_ - 1, max(0, (int)px));   // trunc like .astype(int32); pos >= 0
    int y = min(BOARD_ - 1, max(0, (int)py));
    long long cell = ((long long)idx * BOARD_ + y) * BOARD_ + x;

    bool c;
    if (f == 4)      c = ((const unsigned int*)coll)[idx] != 0u;
    else if (f == 2) c = ((const unsigned short*)coll)[idx] != 0u;
    else             c = ((const unsigned char*)coll)[idx] != 0u;

    // collision history cell + safety
    float chv = ch_in[cell] * 0.9f + (c ? 0.1f : 0.0f);
    const long long CHOFF  = 2 * FACN;
    const long long SAFOFF = CHOFF + CHN;
    out[CHOFF + cell] = chv;
    float safety = 1.0f - fminf(fmaxf(chv, 0.0f), 1.0f);
    out[SAFOFF + idx] = safety;
    bool safe = safety > 0.7f;

    // goal alignment, closed form per direction d: (gn . delta[d] + 1) / 2
    float gx = goal[idx * 2 + 0] - px;
    float gy = goal[idx * 2 + 1] - py;
    float n = sqrtf(gx * gx + gy * gy) + 1e-8f;
    float gnx = gx / n, gny = gy / n;
    float align[5];
    align[0] = 0.5f;
    align[1] = (gnx + 1.0f) * 0.5f;
    align[2] = (gny + 1.0f) * 0.5f;
    align[3] = (1.0f - gnx) * 0.5f;
    align[4] = (1.0f - gny) * 0.5f;

    long long cd = cell * D_;
#pragma unroll
    for (int d = 0; d < D_; ++d) {
        bool sp = spike[idx * D_ + d] > 0.5f;
        bool fc = sp && safe && (align[d] > 0.6f);
        bool ic = sp && (!safe || (align[d] <= 0.4f));
        float fv = fac_in[cd + d] * FAC_DECAY + (fc ? 0.0002f : 0.0f);
        float iv = inh_in[cd + d] * INH_DECAY + (ic ? 0.0001f : 0.0f);
        out[cd + d] = fv;
        out[FACN + cd + d] = iv;
    }
}

extern "C" void kernel_launch(void* const* d_in, const int* in_sizes, int n_in,
                              void* d_out, int out_size, void* d_ws, size_t ws_size,
                              hipStream_t stream) {
    const float* pos   = (const float*)d_in[0];
    const float* goal  = (const float*)d_in[1];
    const float* spike = (const float*)d_in[2];
    const float* fac   = (const float*)d_in[3];
    const float* inh   = (const float*)d_in[4];
    const float* ch    = (const float*)d_in[5];
    const void*  coll  = d_in[6];
    float* out = (float*)d_out;

    hipLaunchKernelGGL(bulk_kernel, dim3(2048), dim3(256), 0, stream,
                       (const f32x4*)fac, (const f32x4*)inh, (const f32x4*)ch, (f32x4*)out);
    hipLaunchKernelGGL(agent_kernel, dim3((NAG + 255) / 256), dim3(256), 0, stream,
                       pos, goal, spike, fac, inh, ch, coll, out);
}

// Round 6
// 146.281 us; speedup vs baseline: 1.0326x; 1.0326x over previous
//
#include <hip/hip_runtime.h>

// Problem constants
static constexpr int B_ = 64, A_ = 32, BOARD_ = 64, D_ = 5;
static constexpr long long FACN = (long long)B_ * A_ * BOARD_ * BOARD_ * D_; // 41,943,040
static constexpr long long CHN  = (long long)B_ * A_ * BOARD_ * BOARD_;      // 8,388,608
static constexpr int NAG = B_ * A_;                                          // 2048

// exp(-1/50), exp(-1/20)
static constexpr float FAC_DECAY = 0.9801986733067553f;
static constexpr float INH_DECAY = 0.9512294245007140f;

// Native clang vector type — required by __builtin_nontemporal_load/store.
typedef float f32x4 __attribute__((ext_vector_type(4)));

// Bulk streaming decay: out[fac | inh | ch] = in * scale.
// Block-contiguous chunks: TOT = 23,068,672 vec = 2048 blocks x 11264 vec.
// Region boundaries (FACV, 2*FACV) and group starts are all multiples of 1024,
// so the region pick hoists to once per 1024-vector group (wave-uniform) and
// the inner loop is pure nt-load/scale/nt-store with 4-deep MLP. No tail.
__global__ __launch_bounds__(256) void bulk_kernel(
    const f32x4* __restrict__ fac_in, const f32x4* __restrict__ inh_in,
    const f32x4* __restrict__ ch_in, f32x4* __restrict__ out)
{
    const int FACV = (int)(FACN / 4);       // 10,485,760 vectors (= 10240*1024)
    const int C = 11264;                    // vectors per block (= 11*1024)
    const int t = threadIdx.x;
    const int base = blockIdx.x * C;

    for (int off = 0; off < C; off += 1024) {
        const int G = base + off;           // multiple of 1024 -> group never straddles a region
        const f32x4* __restrict__ s;
        float c;
        if (G < FACV)            { s = fac_in + G;            c = FAC_DECAY; }
        else if (G < 2 * FACV)   { s = inh_in + (G - FACV);   c = INH_DECAY; }
        else                     { s = ch_in + (G - 2 * FACV); c = 0.9f; }
        f32x4* __restrict__ d = out + G;

        f32x4 a = __builtin_nontemporal_load(&s[t]);
        f32x4 b = __builtin_nontemporal_load(&s[t + 256]);
        f32x4 e = __builtin_nontemporal_load(&s[t + 512]);
        f32x4 f = __builtin_nontemporal_load(&s[t + 768]);
        a *= c; b *= c; e *= c; f *= c;
        __builtin_nontemporal_store(a, &d[t]);
        __builtin_nontemporal_store(b, &d[t + 256]);
        __builtin_nontemporal_store(e, &d[t + 512]);
        __builtin_nontemporal_store(f, &d[t + 768]);
    }
}

// Per-agent tail: the scatter index (b,a,y,x) is unique per (b,a) -> no atomics.
// Runs after bulk_kernel (stream-ordered); overwrites the scattered cells with
// decayed+added values computed from the ORIGINAL inputs, and writes safety.
// 32 blocks x 64 threads to spread the scattered-load latency over 32 CUs.
// The collisions-dtype sniff is per-block parallel (reads 2048 bytes = smallest
// possible encoding of the 2048-entry bool buffer -> always in bounds).
__global__ __launch_bounds__(64) void agent_kernel(
    const float* __restrict__ pos, const float* __restrict__ goal,
    const float* __restrict__ spike,
    const float* __restrict__ fac_in, const float* __restrict__ inh_in,
    const float* __restrict__ ch_in,
    const void* __restrict__ coll,
    float* __restrict__ out)
{
    // ---- parallel dtype sniff (benign-race shared flags) ----
    __shared__ int s_w4, s_h2;
    if (threadIdx.x == 0) { s_w4 = 1; s_h2 = 1; }
    __syncthreads();
    {
        const unsigned int* cw = (const unsigned int*)coll;
        for (int k = threadIdx.x; k < 512; k += 64) {
            unsigned int w = cw[k];
            if (!(w == 0u || w == 1u || w == 0x3F800000u)) s_w4 = 0;
            unsigned int lo = w & 0xFFFFu, hi = w >> 16;
            if (!((lo == 0u || lo == 1u || lo == 0x3F80u || lo == 0x3C00u) &&
                  (hi == 0u || hi == 1u || hi == 0x3F80u || hi == 0x3C00u)))
                s_h2 = 0;
        }
    }
    __syncthreads();
    const int f = s_w4 ? 4 : (s_h2 ? 2 : 1);

    int idx = blockIdx.x * blockDim.x + threadIdx.x;
    if (idx >= NAG) return;

    float px = pos[idx * 2 + 0];
    float py = pos[idx * 2 + 1];
    int x = min(BOARD_ - 1, max(0, (int)px));   // trunc like .astype(int32); pos >= 0
    int y = min(BOARD_ - 1, max(0, (int)py));
    long long cell = ((long long)idx * BOARD_ + y) * BOARD_ + x;

    bool c;
    if (f == 4)      c = ((const unsigned int*)coll)[idx] != 0u;
    else if (f == 2) c = ((const unsigned short*)coll)[idx] != 0u;
    else             c = ((const unsigned char*)coll)[idx] != 0u;

    // collision history cell + safety
    float chv = ch_in[cell] * 0.9f + (c ? 0.1f : 0.0f);
    const long long CHOFF  = 2 * FACN;
    const long long SAFOFF = CHOFF + CHN;
    out[CHOFF + cell] = chv;
    float safety = 1.0f - fminf(fmaxf(chv, 0.0f), 1.0f);
    out[SAFOFF + idx] = safety;
    bool safe = safety > 0.7f;

    // goal alignment, closed form per direction d: (gn . delta[d] + 1) / 2
    float gx = goal[idx * 2 + 0] - px;
    float gy = goal[idx * 2 + 1] - py;
    float n = sqrtf(gx * gx + gy * gy) + 1e-8f;
    float gnx = gx / n, gny = gy / n;
    float align[5];
    align[0] = 0.5f;
    align[1] = (gnx + 1.0f) * 0.5f;
    align[2] = (gny + 1.0f) * 0.5f;
    align[3] = (1.0f - gnx) * 0.5f;
    align[4] = (1.0f - gny) * 0.5f;

    long long cd = cell * D_;
#pragma unroll
    for (int d = 0; d < D_; ++d) {
        bool sp = spike[idx * D_ + d] > 0.5f;
        bool fc = sp && safe && (align[d] > 0.6f);
        bool ic = sp && (!safe || (align[d] <= 0.4f));
        float fv = fac_in[cd + d] * FAC_DECAY + (fc ? 0.0002f : 0.0f);
        float iv = inh_in[cd + d] * INH_DECAY + (ic ? 0.0001f : 0.0f);
        out[cd + d] = fv;
        out[FACN + cd + d] = iv;
    }
}

extern "C" void kernel_launch(void* const* d_in, const int* in_sizes, int n_in,
                              void* d_out, int out_size, void* d_ws, size_t ws_size,
                              hipStream_t stream) {
    const float* pos   = (const float*)d_in[0];
    const float* goal  = (const float*)d_in[1];
    const float* spike = (const float*)d_in[2];
    const float* fac   = (const float*)d_in[3];
    const float* inh   = (const float*)d_in[4];
    const float* ch    = (const float*)d_in[5];
    const void*  coll  = d_in[6];
    float* out = (float*)d_out;

    hipLaunchKernelGGL(bulk_kernel, dim3(2048), dim3(256), 0, stream,
                       (const f32x4*)fac, (const f32x4*)inh, (const f32x4*)ch, (f32x4*)out);
    hipLaunchKernelGGL(agent_kernel, dim3(32), dim3(64), 0, stream,
                       pos, goal, spike, fac, inh, ch, coll, out);
}

// Round 7
// 144.569 us; speedup vs baseline: 1.0448x; 1.0118x over previous
//
#include <hip/hip_runtime.h>

// Problem constants
static constexpr int B_ = 64, A_ = 32, BOARD_ = 64, D_ = 5;
static constexpr long long FACN = (long long)B_ * A_ * BOARD_ * BOARD_ * D_; // 41,943,040
static constexpr long long CHN  = (long long)B_ * A_ * BOARD_ * BOARD_;      // 8,388,608
static constexpr int NAG = B_ * A_;                                          // 2048

// exp(-1/50), exp(-1/20)
static constexpr float FAC_DECAY = 0.9801986733067553f;
static constexpr float INH_DECAY = 0.9512294245007140f;

// Native clang vector type — required by __builtin_nontemporal_load/store.
typedef float f32x4 __attribute__((ext_vector_type(4)));

// Bulk streaming decay: out[fac | inh | ch] = in * scale.
// Block-contiguous chunks: TOT = 23,068,672 vec = 2048 blocks x 11264 vec.
// Group starts and region boundaries are multiples of 1024 -> region pick is
// wave-uniform per group. SOFTWARE-PIPELINED: group k+1's 4 loads issue BEFORE
// group k's stores, so the read stream never drains between groups.
__global__ __launch_bounds__(256) void bulk_kernel(
    const f32x4* __restrict__ fac_in, const f32x4* __restrict__ inh_in,
    const f32x4* __restrict__ ch_in, f32x4* __restrict__ out)
{
    const int FACV = (int)(FACN / 4);       // 10,485,760 vectors (= 10240*1024)
    const int C = 11264;                    // vectors per block (= 11*1024)
    const int t = threadIdx.x;
    const int base = blockIdx.x * C;

    auto ldgrp = [&](int G, f32x4 v[4], float& c) {
        const f32x4* __restrict__ s;
        if (G < FACV)          { s = fac_in + G;             c = FAC_DECAY; }
        else if (G < 2 * FACV) { s = inh_in + (G - FACV);    c = INH_DECAY; }
        else                   { s = ch_in + (G - 2 * FACV); c = 0.9f; }
        v[0] = __builtin_nontemporal_load(&s[t]);
        v[1] = __builtin_nontemporal_load(&s[t + 256]);
        v[2] = __builtin_nontemporal_load(&s[t + 512]);
        v[3] = __builtin_nontemporal_load(&s[t + 768]);
    };

    f32x4 v[4]; float c;
    ldgrp(base, v, c);
    int off = 0;
    while (true) {
        f32x4 w[4]; float c2;
        const int noff = off + 1024;
        if (noff < C) ldgrp(base + noff, w, c2);   // prefetch next group first
        f32x4* __restrict__ d = out + base + off;
        __builtin_nontemporal_store(v[0] * c, &d[t]);
        __builtin_nontemporal_store(v[1] * c, &d[t + 256]);
        __builtin_nontemporal_store(v[2] * c, &d[t + 512]);
        __builtin_nontemporal_store(v[3] * c, &d[t + 768]);
        if (noff >= C) break;
        v[0] = w[0]; v[1] = w[1]; v[2] = w[2]; v[3] = w[3]; c = c2;
        off = noff;
    }
}

// Per-agent tail, 8 threads per agent (d-slot split) -> 16384 threads.
// The scatter index (b,a,y,x) is unique per (b,a) -> no atomics; this kernel
// runs after bulk_kernel (stream-ordered) and overwrites the scattered cells
// with values computed from the ORIGINAL inputs.
// Slots d=0..4: fac/inh cell d. Slot d=5: ch cell + safety. d=6,7: idle.
// The collisions-dtype sniff is per-block parallel (reads 2048 bytes = the
// smallest possible encoding of the 2048-entry bool buffer -> always in bounds).
__global__ __launch_bounds__(64) void agent_kernel(
    const float* __restrict__ pos, const float* __restrict__ goal,
    const float* __restrict__ spike,
    const float* __restrict__ fac_in, const float* __restrict__ inh_in,
    const float* __restrict__ ch_in,
    const void* __restrict__ coll,
    float* __restrict__ out)
{
    // ---- parallel dtype sniff (benign-race shared flags) ----
    __shared__ int s_w4, s_h2;
    if (threadIdx.x == 0) { s_w4 = 1; s_h2 = 1; }
    __syncthreads();
    {
        const unsigned int* cw = (const unsigned int*)coll;
        for (int k = threadIdx.x; k < 512; k += 64) {
            unsigned int w = cw[k];
            if (!(w == 0u || w == 1u || w == 0x3F800000u)) s_w4 = 0;
            unsigned int lo = w & 0xFFFFu, hi = w >> 16;
            if (!((lo == 0u || lo == 1u || lo == 0x3F80u || lo == 0x3C00u) &&
                  (hi == 0u || hi == 1u || hi == 0x3F80u || hi == 0x3C00u)))
                s_h2 = 0;
        }
    }
    __syncthreads();
    const int f = s_w4 ? 4 : (s_h2 ? 2 : 1);

    const int tid = blockIdx.x * 64 + threadIdx.x;
    const int idx = tid >> 3;          // agent
    const int d   = tid & 7;           // slot
    if (idx >= NAG || d >= 6) return;

    float px = pos[idx * 2 + 0];
    float py = pos[idx * 2 + 1];
    int x = min(BOARD_ - 1, max(0, (int)px));   // trunc like .astype(int32); pos >= 0
    int y = min(BOARD_ - 1, max(0, (int)py));
    long long cell = ((long long)idx * BOARD_ + y) * BOARD_ + x;

    bool c;
    if (f == 4)      c = ((const unsigned int*)coll)[idx] != 0u;
    else if (f == 2) c = ((const unsigned short*)coll)[idx] != 0u;
    else             c = ((const unsigned char*)coll)[idx] != 0u;

    float chv = ch_in[cell] * 0.9f + (c ? 0.1f : 0.0f);
    float safety = 1.0f - fminf(fmaxf(chv, 0.0f), 1.0f);

    if (d == 5) {
        const long long CHOFF  = 2 * FACN;
        const long long SAFOFF = CHOFF + CHN;
        out[CHOFF + cell] = chv;
        out[SAFOFF + idx] = safety;
        return;
    }

    bool safe = safety > 0.7f;

    // goal alignment for this direction: (gn . delta[d] + 1) / 2
    float gx = goal[idx * 2 + 0] - px;
    float gy = goal[idx * 2 + 1] - py;
    float n = sqrtf(gx * gx + gy * gy) + 1e-8f;
    float gnx = gx / n, gny = gy / n;
    float al = (d == 0) ? 0.5f
             : (d == 1) ? (gnx + 1.0f) * 0.5f
             : (d == 2) ? (gny + 1.0f) * 0.5f
             : (d == 3) ? (1.0f - gnx) * 0.5f
                        : (1.0f - gny) * 0.5f;

    long long cd = cell * D_ + d;
    bool sp = spike[idx * D_ + d] > 0.5f;
    bool fc = sp && safe && (al > 0.6f);
    bool ic = sp && (!safe || (al <= 0.4f));
    out[cd]        = fac_in[cd] * FAC_DECAY + (fc ? 0.0002f : 0.0f);
    out[FACN + cd] = inh_in[cd] * INH_DECAY + (ic ? 0.0001f : 0.0f);
}

extern "C" void kernel_launch(void* const* d_in, const int* in_sizes, int n_in,
                              void* d_out, int out_size, void* d_ws, size_t ws_size,
                              hipStream_t stream) {
    const float* pos   = (const float*)d_in[0];
    const float* goal  = (const float*)d_in[1];
    const float* spike = (const float*)d_in[2];
    const float* fac   = (const float*)d_in[3];
    const float* inh   = (const float*)d_in[4];
    const float* ch    = (const float*)d_in[5];
    const void*  coll  = d_in[6];
    float* out = (float*)d_out;

    hipLaunchKernelGGL(bulk_kernel, dim3(2048), dim3(256), 0, stream,
                       (const f32x4*)fac, (const f32x4*)inh, (const f32x4*)ch, (f32x4*)out);
    hipLaunchKernelGGL(agent_kernel, dim3(256), dim3(64), 0, stream,
                       pos, goal, spike, fac, inh, ch, coll, out);
}